// Round 3
// baseline (329.240 us; speedup 1.0000x reference)
//
#include <hip/hip_runtime.h>
#include <math.h>

#define BSZ 8
#define MROWS 64
#define NCOLS 4096
#define KSEL 32
#define EPSF 1e-20f
#define NEG_INF (-3.402823466e+38f)

typedef float floatx4 __attribute__((ext_vector_type(4)));

// ---------------------------------------------------------------------------
// Fused one-hot top-32, restructured for stream overlap.
// Grid: 2048 blocks = 4 blocks per (b,m) row; block g owns k-rows [8g,8g+8).
// 8 blocks/CU (16.4 KiB LDS each), 32 waves/CU = full occupancy.
//
//   waves 1-3: stream zeros into this block's 8 k-rows STARTING AT CYCLE 0
//              (no dependence on input). 24 streaming waves/CU.
//   wave 0:    stages the perturbed row into swizzled LDS alone (16 float4
//              pairs/lane, ~2us of logf), then runs the proven barrier-free
//              iterative top-32 + rank (redundant across the row's 4 blocks;
//              hidden under the zero stream). Writes si[32].
//   barrier;   wave 0 lanes 0-7 scatter this block's 8 ones.
//
// Swizzle: column col lives at (col & ~63) | ((col + (col>>6)) & 63).
// Lane l owns chunk [64l, 64l+64). Per-lane chunk scan and all-lanes
// single-chunk rescan are both 2-lanes-per-bank (free on gfx950, m136).
// ---------------------------------------------------------------------------
__global__ __launch_bounds__(256) void topk_onehot_kernel(
    const float* __restrict__ logits,   // (64, 4096)
    const float* __restrict__ u,        // (8, 64, 4096)
    float* __restrict__ out)            // (8, 64, 32, 4096)
{
    __shared__ float vals[NCOLS];       // 16 KiB
    __shared__ int   si[KSEL];

    const int bid  = blockIdx.x;
    const int r    = bid >> 2;          // row = b*64 + m
    const int g    = bid & 3;           // k-row group [8g, 8g+8)
    const int m    = r & (MROWS - 1);
    const int tid  = threadIdx.x;
    const int lane = tid & 63;
    const int w    = tid >> 6;

    float* oslab = out + ((size_t)r * KSEL + (g << 3)) * NCOLS;  // 8 k-rows

    if (w != 0) {
        // ---- waves 1-3: zero-stream 8 rows (8192 float4s over 192 lanes),
        // independent of everything -> starts immediately. ----
        const floatx4 z4 = {0.f, 0.f, 0.f, 0.f};
        floatx4* o4 = (floatx4*)oslab;
        const int z = tid - 64;                  // 0..191, wave-contiguous
        #pragma unroll
        for (int j = 0; j < 42; ++j)             // 42*192 = 8064
            o4[z + j * 192] = z4;
        if (z < 128) o4[8064 + z] = z4;          // remainder 128
    } else {
        // ---- wave 0: stage whole row alone (swizzled LDS) ----
        const float4* u4 = (const float4*)(u + (size_t)r * NCOLS);
        const float4* l4 = (const float4*)(logits + (size_t)m * NCOLS);
        #pragma unroll
        for (int c = 0; c < 16; ++c) {
            int q = (c << 6) + lane;             // float4 index, coalesced
            float4 uu = u4[q];
            float4 lg = l4[q];
            float px = lg.x - 0.001f * logf(-logf(uu.x + EPSF) + EPSF);
            float py = lg.y - 0.001f * logf(-logf(uu.y + EPSF) + EPSF);
            float pz = lg.z - 0.001f * logf(-logf(uu.z + EPSF) + EPSF);
            float pw = lg.w - 0.001f * logf(-logf(uu.w + EPSF) + EPSF);
            int col   = q << 2;
            int chunk = col >> 6;                // same chunk for all 4 cols
            int base  = chunk << 6;
            vals[base + ((col + 0 + chunk) & 63)] = px;
            vals[base + ((col + 1 + chunk) & 63)] = py;
            vals[base + ((col + 2 + chunk) & 63)] = pz;
            vals[base + ((col + 3 + chunk) & 63)] = pw;
        }
        // same-wave DS pipe is in-order: staging writes complete before the
        // scan's reads return -> no barrier needed (single-wave pipeline).

        // ---- selection (proven iterative top-32) ----
        float lmax = NEG_INF;
        int   lidx = 0x7FFFFFFF;
        {
            const int cb = lane << 6;
            #pragma unroll 8
            for (int c = 0; c < 64; ++c) {       // ascending col => low-idx ties
                float v = vals[cb + ((c + lane) & 63)];
                if (v > lmax) { lmax = v; lidx = cb + c; }
            }
        }
        unsigned long long removed = 0ull;       // removal mask for OWN chunk
        int sel_reg = 0x7FFFFFFF;                // lane i (<32) holds winner i
        for (int it = 0; it < KSEL; ++it) {
            float bv = lmax; int bi = lidx;
            #pragma unroll
            for (int off = 32; off; off >>= 1) {
                float ov = __shfl_xor(bv, off);
                int   oi = __shfl_xor(bi, off);
                if (ov > bv || (ov == bv && oi < bi)) { bv = ov; bi = oi; }
            }
            if (lane == it) sel_reg = bi;

            const int wl = bi >> 6;              // winner chunk / owner lane
            if (lane == wl) removed |= (1ull << (bi & 63));

            unsigned long long rm = __shfl(removed, wl);
            float nv = vals[(wl << 6) + ((lane + wl) & 63)];
            int   ni = (wl << 6) + lane;
            if ((rm >> lane) & 1ull) nv = NEG_INF;
            #pragma unroll
            for (int off = 32; off; off >>= 1) {
                float ov = __shfl_xor(nv, off);
                int   oi = __shfl_xor(ni, off);
                if (ov > nv || (ov == nv && oi < ni)) { nv = ov; ni = oi; }
            }
            if (lane == wl) { lmax = nv; lidx = ni; }
        }
        // rank = ascending position (winners distinct)
        int myw = sel_reg;
        int rank = 0;
        #pragma unroll
        for (int j = 0; j < KSEL; ++j) {
            int wj = __shfl(sel_reg, j);
            rank += (wj < myw) ? 1 : 0;
        }
        if (lane < KSEL) si[rank] = myw;         // same-wave DS pipe: in-order
    }

    __syncthreads();   // zeros drained (vmcnt(0) before s_barrier) + si visible

    // ---- wave 0: scatter this block's 8 ones over the zeroed slab ----
    if (tid < 8) {
        oslab[(size_t)tid * NCOLS + (size_t)si[(g << 3) + tid]] = 1.0f;
    }
}

extern "C" void kernel_launch(void* const* d_in, const int* in_sizes, int n_in,
                              void* d_out, int out_size, void* d_ws, size_t ws_size,
                              hipStream_t stream) {
    const float* logits = (const float*)d_in[0];   // (64, 4096) fp32
    const float* u      = (const float*)d_in[1];   // (8, 64, 4096) fp32
    float* out          = (float*)d_out;           // (8, 64, 32, 4096) fp32

    topk_onehot_kernel<<<4 * BSZ * MROWS, 256, 0, stream>>>(logits, u, out);
}